// Round 15
// baseline (299.687 us; speedup 1.0000x reference)
//
#include <hip/hip_runtime.h>
#include <hip/hip_bf16.h>
#include <stdint.h>

#define DEVI __device__ __forceinline__

typedef float f32x4 __attribute__((ext_vector_type(4)));
typedef float f32x16 __attribute__((ext_vector_type(16)));
typedef short bf16x8 __attribute__((ext_vector_type(8)));

typedef __attribute__((address_space(3))) unsigned int as3_u32;
typedef __attribute__((address_space(1))) unsigned int as1_u32;

DEVI void gload16(const void* g, void* l) {
  __builtin_amdgcn_global_load_lds((const as1_u32*)g, (as3_u32*)l, 16, 0, 0);
}

DEVI unsigned short bf16r(float f) {
  union { float f; unsigned int u; } v; v.f = f;
  unsigned int u = v.u;
  return (unsigned short)((u + 0x7FFFu + ((u >> 16) & 1u)) >> 16);
}

DEVI float bf2f(unsigned short u) {
  unsigned int x = ((unsigned int)u) << 16;
  union { unsigned int u; float f; } v; v.u = x;
  return v.f;
}

DEVI unsigned int pkbf16(float a, float b) {
  __hip_bfloat162 h = __float22bfloat162_rn(make_float2(a, b));
  return *(unsigned int*)&h;
}

// ------- merged: weight prep (blocks 0..639) + x l2norm (blocks 640..8831) ---
struct PrepArgs {
  const float* w[10];
  const float* b1[3];
  const float* b2[3];
};

__global__ __launch_bounds__(256) void prep_l2norm_kernel(PrepArgs pa, unsigned short* wt,
                                                          float* qb1, float* qb2,
                                                          const float* __restrict__ x,
                                                          unsigned short* __restrict__ xn) {
  const int bid = blockIdx.x;
  if (bid < 640) {
    __shared__ float lt[64][65];
    const int slot = bid >> 6, r = bid & 63;
    const int n0 = (r & 7) * 64, k0 = (r >> 3) * 64;
    const float* W = pa.w[slot];
    for (int it = 0; it < 16; it++) {
      int idx = it * 256 + threadIdx.x;
      int kr = idx >> 6, nc = idx & 63;
      lt[kr][nc] = W[(long)(k0 + kr) * 512 + n0 + nc];
    }
    __syncthreads();
    unsigned short* dst = wt + (long)slot * 512 * 512;
    for (int it = 0; it < 16; it++) {
      int idx = it * 256 + threadIdx.x;
      int nr = idx >> 6, kc = idx & 63;
      dst[(long)(n0 + nr) * 512 + k0 + kc] = bf16r(lt[kc][nr]);
    }
    if (r == 0) {
      if (slot < 3) {
        for (int i = threadIdx.x; i < 512; i += 256) qb1[slot * 512 + i] = pa.b1[slot][i];
      } else if (slot >= 6 && slot < 9) {
        for (int i = threadIdx.x; i < 512; i += 256) qb2[(slot - 6) * 512 + i] = pa.b2[slot - 6][i];
      }
    }
  } else {
    const long row = bid - 640;
    const float* xr = x + row * 512;
    float v0 = xr[threadIdx.x], v1 = xr[threadIdx.x + 256];
    float ss = v0 * v0 + v1 * v1;
    #pragma unroll
    for (int off = 32; off > 0; off >>= 1) ss += __shfl_down(ss, off, 64);
    __shared__ float red[4];
    __shared__ float sc[1];
    int w = threadIdx.x >> 6, ln = threadIdx.x & 63;
    if (ln == 0) red[w] = ss;
    __syncthreads();
    if (threadIdx.x == 0) {
      float S = red[0] + red[1] + red[2] + red[3];
      sc[0] = 1.0f / fmaxf(sqrtf(S), 1e-12f);
    }
    __syncthreads();
    float s = sc[0];
    xn[row * 512 + threadIdx.x] = bf16r(v0 * s);
    xn[row * 512 + threadIdx.x + 256] = bf16r(v1 * s);
  }
}

// ---------------- GEMM 128x128: C = A x Bt^T + bias --------------------------
// EPI: 1 = bf16 out, 2 = bf16 out + relu,
//      3 = bf16 out; cols >=1024 are V -> written transposed into vtout
template <int EPI>
__global__ __launch_bounds__(256) void gemm_bt(const unsigned short* __restrict__ A,
                                               const unsigned short* __restrict__ Bt,
                                               const float* __restrict__ bias,
                                               void* __restrict__ Cv, int K, int N,
                                               unsigned short* __restrict__ vtout) {
  __shared__ unsigned short ldsA[128 * 64];
  __shared__ unsigned short ldsB[128 * 64];
  const int tid = threadIdx.x, w = tid >> 6, ln = tid & 63;
  const int bm = blockIdx.x, bn = blockIdx.y;
  const int wm = (w >> 1) * 64, wn = (w & 1) * 64;
  const f32x4 zf = {0.f, 0.f, 0.f, 0.f};
  f32x4 acc[4][4];
  #pragma unroll
  for (int i = 0; i < 4; i++)
    #pragma unroll
    for (int j = 0; j < 4; j++) acc[i][j] = zf;
  const int r8 = ln >> 3, s8 = ln & 7;
  for (int kt = 0; kt < K; kt += 64) {
    #pragma unroll
    for (int i = 0; i < 4; i++) {
      int row = w * 32 + i * 8 + r8;
      gload16(A + (long)(bm * 128 + row) * K + kt + s8 * 8, &ldsA[(w * 32 + i * 8) * 64]);
      gload16(Bt + (long)(bn * 128 + row) * K + kt + s8 * 8, &ldsB[(w * 32 + i * 8) * 64]);
    }
    __syncthreads();
    #pragma unroll
    for (int kk = 0; kk < 2; kk++) {
      bf16x8 af[4], bfr[4];
      #pragma unroll
      for (int mf = 0; mf < 4; mf++) {
        int row = wm + mf * 16 + (ln & 15);
        af[mf] = *(const bf16x8*)&ldsA[row * 64 + kk * 32 + (ln >> 4) * 8];
      }
      #pragma unroll
      for (int nf = 0; nf < 4; nf++) {
        int row = wn + nf * 16 + (ln & 15);
        bfr[nf] = *(const bf16x8*)&ldsB[row * 64 + kk * 32 + (ln >> 4) * 8];
      }
      #pragma unroll
      for (int mf = 0; mf < 4; mf++)
        #pragma unroll
        for (int nf = 0; nf < 4; nf++)
          acc[mf][nf] = __builtin_amdgcn_mfma_f32_16x16x32_bf16(af[mf], bfr[nf], acc[mf][nf], 0, 0, 0);
    }
    __syncthreads();
  }
  const int g = ln >> 4, c = ln & 15;
  #pragma unroll
  for (int mf = 0; mf < 4; mf++) {
    #pragma unroll
    for (int nf = 0; nf < 4; nf++) {
      int col = bn * 128 + wn + nf * 16 + c;
      float bv = bias[col];
      if (EPI == 3 && col >= 1024) {
        long row0 = bm * 128 + wm + mf * 16 + g * 4;
        int b = (int)(row0 >> 11), s = (int)(row0 & 2047);
        int vc = col - 1024, h = vc >> 6, hd = vc & 63;
        ushort4 o;
        o.x = bf16r(acc[mf][nf][0] + bv);
        o.y = bf16r(acc[mf][nf][1] + bv);
        o.z = bf16r(acc[mf][nf][2] + bv);
        o.w = bf16r(acc[mf][nf][3] + bv);
        *(ushort4*)(vtout + ((long)((b * 8 + h) * 64 + hd)) * 2048 + s) = o;
      } else {
        #pragma unroll
        for (int j = 0; j < 4; j++) {
          long row = bm * 128 + wm + mf * 16 + g * 4 + j;
          float v = acc[mf][nf][j] + bv;
          if (EPI == 2) v = v > 0.f ? v : 0.f;
          ((unsigned short*)Cv)[row * N + col] = bf16r(v);
        }
      }
    }
  }
}

// ---------------- GEMM 128x64 tile (for N=512 chains) ------------------------
template <int EPI>  // 1 = bf16 out, 2 = bf16 + relu
__global__ __launch_bounds__(256) void gemm_bt64(const unsigned short* __restrict__ A,
                                                 const unsigned short* __restrict__ Bt,
                                                 const float* __restrict__ bias,
                                                 void* __restrict__ Cv, int K, int N) {
  __shared__ unsigned short ldsA[128 * 64];
  __shared__ unsigned short ldsB[64 * 64];
  const int tid = threadIdx.x, w = tid >> 6, ln = tid & 63;
  const int bm = blockIdx.x, bn = blockIdx.y;
  const int wm = (w >> 1) * 64, wn = (w & 1) * 32;
  const f32x4 zf = {0.f, 0.f, 0.f, 0.f};
  f32x4 acc[4][2];
  #pragma unroll
  for (int i = 0; i < 4; i++)
    #pragma unroll
    for (int j = 0; j < 2; j++) acc[i][j] = zf;
  const int r8 = ln >> 3, s8 = ln & 7;
  for (int kt = 0; kt < K; kt += 64) {
    #pragma unroll
    for (int i = 0; i < 6; i++) {
      int jj = w * 6 + i;
      if (jj < 16) {
        gload16(A + (long)(bm * 128 + jj * 8 + r8) * K + kt + s8 * 8, &ldsA[jj * 512]);
      } else {
        int jb = jj - 16;
        gload16(Bt + (long)(bn * 64 + jb * 8 + r8) * K + kt + s8 * 8, &ldsB[jb * 512]);
      }
    }
    __syncthreads();
    #pragma unroll
    for (int kk = 0; kk < 2; kk++) {
      bf16x8 af[4], bfr[2];
      #pragma unroll
      for (int mf = 0; mf < 4; mf++)
        af[mf] = *(const bf16x8*)&ldsA[(wm + mf * 16 + (ln & 15)) * 64 + kk * 32 + (ln >> 4) * 8];
      #pragma unroll
      for (int nf = 0; nf < 2; nf++)
        bfr[nf] = *(const bf16x8*)&ldsB[(wn + nf * 16 + (ln & 15)) * 64 + kk * 32 + (ln >> 4) * 8];
      #pragma unroll
      for (int mf = 0; mf < 4; mf++)
        #pragma unroll
        for (int nf = 0; nf < 2; nf++)
          acc[mf][nf] = __builtin_amdgcn_mfma_f32_16x16x32_bf16(af[mf], bfr[nf], acc[mf][nf], 0, 0, 0);
    }
    __syncthreads();
  }
  const int g = ln >> 4, c = ln & 15;
  #pragma unroll
  for (int mf = 0; mf < 4; mf++) {
    #pragma unroll
    for (int nf = 0; nf < 2; nf++) {
      int col = bn * 64 + wn + nf * 16 + c;
      float bv = bias[col];
      #pragma unroll
      for (int j = 0; j < 4; j++) {
        long row = bm * 128 + wm + mf * 16 + g * 4 + j;
        float v = acc[mf][nf][j] + bv;
        if (EPI == 2) v = v > 0.f ? v : 0.f;
        ((unsigned short*)Cv)[row * N + col] = bf16r(v);
      }
    }
  }
}

// ---------------- fused attention, FULL-K, 32x32 MFMA, in-register P ---------
// 3-buffer rotation -> ONE barrier per iteration (hazard window spans 2 iters).
__global__ __launch_bounds__(256, 4) void attn_kernel(
    const unsigned short* __restrict__ qkv,
    const unsigned short* __restrict__ vt,
    const float* __restrict__ mask,
    unsigned short* __restrict__ ao) {
  const int tid = threadIdx.x, w = tid >> 6, ln = tid & 63;
  const int lo = ln & 31, hi = ln >> 5;
  // XCD-aware bijective swizzle (512 = 8 x 64)
  const int bid = blockIdx.x + 16 * blockIdx.y;
  const int swz = (bid & 7) * 64 + (bid >> 3);
  const int qb = swz & 15, bh = swz >> 4;
  const int b = bh >> 3, h = bh & 7;
  const int q0 = qb * 128 + w * 32;
  const unsigned short* qp = qkv + (long)(b * 2048) * 1536 + h * 64;
  const unsigned short* kp = qp + 512;
  const unsigned short* vtp = vt + (long)bh * 64 * 2048;
  const float* mp = mask + b * 2048;

  __shared__ unsigned short sbuf[3][4096];   // 8KB per buffer
  __shared__ float mbuf[2048];
  __shared__ int mflag;

  {
    float acc = 0.f;
    #pragma unroll
    for (int i = 0; i < 8; i++) {
      float mv = mp[i * 256 + tid];
      mbuf[i * 256 + tid] = mv;
      acc += fabsf(mv);
    }
    if (tid == 0) mflag = 0;
    __syncthreads();
    if (acc != 0.f) mflag = 1;
    __syncthreads();
  }
  const bool anymask = (mflag != 0);

  const int jj0 = w * 2;
  const char *src0, *src1;
  long step;
  if (w < 2) {
    int r0 = jj0 * 8 + (ln >> 3), r1 = r0 + 8, s = ln & 7;
    src0 = (const char*)kp + 2L * ((long)r0 * 1536 + ((s ^ (r0 & 7)) * 8));
    src1 = (const char*)kp + 2L * ((long)r1 * 1536 + ((s ^ (r1 & 7)) * 8));
    step = 32L * 1536 * 2;
  } else {
    int j0 = (w - 2) * 2;
    int r0 = j0 * 16 + (ln >> 2), r1 = r0 + 16, s = ln & 3;
    src0 = (const char*)vtp + 2L * ((long)r0 * 2048 + ((s ^ ((r0 >> 1) & 3)) * 8));
    src1 = (const char*)vtp + 2L * ((long)r1 * 2048 + ((s ^ ((r1 >> 1) & 3)) * 8));
    step = 64;
  }
  unsigned short* const da0 = &sbuf[0][jj0 * 512]; unsigned short* const db0 = da0 + 512;
  unsigned short* const da1 = &sbuf[1][jj0 * 512]; unsigned short* const db1 = da1 + 512;
  unsigned short* const da2 = &sbuf[2][jj0 * 512]; unsigned short* const db2 = da2 + 512;

  int koffe[4];
  #pragma unroll
  for (int t = 0; t < 4; t++)
    koffe[t] = lo * 64 + (((t * 2 + hi) ^ (lo & 7)) * 8);
  int voffe[4];
  #pragma unroll
  for (int stt = 0; stt < 2; stt++)
    #pragma unroll
    for (int tau = 0; tau < 2; tau++) {
      int vr = tau * 32 + lo;
      voffe[stt * 2 + tau] = 2048 + vr * 32 + ((((stt * 2 + hi) ^ ((vr >> 1) & 3))) * 8);
    }

  bf16x8 qf[4];
  #pragma unroll
  for (int t = 0; t < 4; t++)
    qf[t] = *(const bf16x8*)(qp + (long)(q0 + lo) * 1536 + t * 16 + hi * 8);

  f32x16 oacc[2];
  #pragma unroll
  for (int t = 0; t < 2; t++)
    #pragma unroll
    for (int r = 0; r < 16; r++) oacc[t][r] = 0.f;
  float lsum = 0.f;
  const f32x16 zf16 = oacc[0];
  const float SC = 0.18033688011112042f;  // 0.125 * log2(e)

  // prologue: stage iter-0 data into buf0
  gload16(src0, da0);
  gload16(src1, db0);
  src0 += step; src1 += step;

#define ATTN_BODY(CURB, DA, DB, ITOFF, STAGE_NEXT)                              \
  {                                                                             \
    if (STAGE_NEXT) {                                                           \
      gload16(src0, DA);                                                        \
      gload16(src1, DB);                                                        \
      src0 += step; src1 += step;                                               \
      asm volatile("s_waitcnt vmcnt(2)" ::: "memory");                          \
    } else {                                                                    \
      asm volatile("s_waitcnt vmcnt(0)" ::: "memory");                          \
    }                                                                           \
    __builtin_amdgcn_s_barrier();                                               \
    __builtin_amdgcn_sched_barrier(0);                                          \
    f32x16 sacc = zf16;                                                         \
    _Pragma("unroll")                                                           \
    for (int t = 0; t < 4; t++) {                                               \
      bf16x8 kf = *(const bf16x8*)&sbuf[CURB][koffe[t]];                        \
      sacc = __builtin_amdgcn_mfma_f32_32x32x16_bf16(kf, qf[t], sacc, 0, 0, 0); \
    }                                                                           \
    float e[16];                                                                \
    _Pragma("unroll")                                                           \
    for (int r = 0; r < 16; r++) e[r] = sacc[r] * SC;                           \
    if (anymask) {                                                              \
      float mval = mbuf[(ITOFF) + lo];                                          \
      _Pragma("unroll")                                                         \
      for (int r = 0; r < 16; r++)                                              \
        e[r] -= 1.4426950408889634e30f *                                        \
                __shfl(mval, (r & 3) + 8 * (r >> 2) + 4 * hi, 64);              \
    }                                                                           \
    _Pragma("unroll")                                                           \
    for (int r = 0; r < 16; r++) e[r] = __builtin_amdgcn_exp2f(e[r]);           \
    _Pragma("unroll")                                                           \
    for (int r = 0; r < 16; r++) lsum += e[r];                                  \
    unsigned int cv[8];                                                         \
    _Pragma("unroll")                                                           \
    for (int i = 0; i < 8; i++) cv[i] = pkbf16(e[2 * i], e[2 * i + 1]);         \
    _Pragma("unroll")                                                           \
    for (int stt = 0; stt < 2; stt++) {                                         \
      unsigned int pf[4];                                                       \
      {                                                                         \
        auto r0_ = __builtin_amdgcn_permlane32_swap(cv[stt * 4 + 0],            \
                                                    cv[stt * 4 + 2], false, false); \
        auto r1_ = __builtin_amdgcn_permlane32_swap(cv[stt * 4 + 1],            \
                                                    cv[stt * 4 + 3], false, false); \
        pf[0] = r0_[0]; pf[1] = r1_[0]; pf[2] = r0_[1]; pf[3] = r1_[1];         \
      }                                                                         \
      bf16x8 pfr = *(const bf16x8*)pf;                                          \
      _Pragma("unroll")                                                         \
      for (int tau = 0; tau < 2; tau++) {                                       \
        bf16x8 vf = *(const bf16x8*)&sbuf[CURB][voffe[stt * 2 + tau]];          \
        oacc[tau] = __builtin_amdgcn_mfma_f32_32x32x16_bf16(vf, pfr, oacc[tau], 0, 0, 0); \
      }                                                                         \
    }                                                                           \
    __builtin_amdgcn_sched_barrier(0);                                          \
  }

  // 64 iterations = 21 x 3 + 1; iter i computes buf[i%3], stages buf[(i+1)%3]
  for (int it3 = 0; it3 < 21; it3++) {
    const int base = it3 * 96;
    ATTN_BODY(0, da1, db1, base, 1)
    ATTN_BODY(1, da2, db2, base + 32, 1)
    ATTN_BODY(2, da0, db0, base + 64, 1)
  }
  ATTN_BODY(0, da1, db1, 2016, 0)
#undef ATTN_BODY

  lsum += __shfl_xor(lsum, 32, 64);
  const float inv = 1.f / lsum;
  unsigned short* ob = ao + ((long)(b * 2048) + q0 + lo) * 512 + h * 64;
  #pragma unroll
  for (int tau = 0; tau < 2; tau++) {
    #pragma unroll
    for (int j = 0; j < 4; j++) {
      ushort4 o;
      o.x = bf16r(oacc[tau][4 * j + 0] * inv);
      o.y = bf16r(oacc[tau][4 * j + 1] * inv);
      o.z = bf16r(oacc[tau][4 * j + 2] * inv);
      o.w = bf16r(oacc[tau][4 * j + 3] * inv);
      *(ushort4*)(ob + tau * 32 + j * 8 + hi * 4) = o;
    }
  }
}

// ---------------- layernorm rows, bf16 in -> bf16 out ------------------------
__global__ __launch_bounds__(256) void ln_kernel(const unsigned short* __restrict__ in,
                                                 const float* __restrict__ gam,
                                                 const float* __restrict__ bet,
                                                 unsigned short* __restrict__ out) {
  const long row = blockIdx.x;
  const unsigned short* x = in + row * 512;
  float v0 = bf2f(x[threadIdx.x]), v1 = bf2f(x[threadIdx.x + 256]);
  float s = v0 + v1, ss = v0 * v0 + v1 * v1;
  #pragma unroll
  for (int off = 32; off > 0; off >>= 1) {
    s += __shfl_down(s, off, 64);
    ss += __shfl_down(ss, off, 64);
  }
  __shared__ float red[8];
  __shared__ float mv[2];
  int w = threadIdx.x >> 6, ln = threadIdx.x & 63;
  if (ln == 0) { red[w] = s; red[w + 4] = ss; }
  __syncthreads();
  if (threadIdx.x == 0) {
    float S = red[0] + red[1] + red[2] + red[3];
    float SS = red[4] + red[5] + red[6] + red[7];
    float mu = S * (1.f / 512.f);
    float var = SS * (1.f / 512.f) - mu * mu;
    mv[0] = mu;
    mv[1] = rsqrtf(var + 1e-5f);
  }
  __syncthreads();
  float mu = mv[0], rs = mv[1];
  float o0 = (v0 - mu) * rs * gam[threadIdx.x] + bet[threadIdx.x];
  float o1 = (v1 - mu) * rs * gam[threadIdx.x + 256] + bet[threadIdx.x + 256];
  out[row * 512 + threadIdx.x] = bf16r(o0);
  out[row * 512 + threadIdx.x + 256] = bf16r(o1);
}

// ---------------- LN2 (bf16 in/out) + fused alpha ----------------------------
__global__ __launch_bounds__(256) void ln2_alpha_kernel(const unsigned short* __restrict__ in,
                                                        const float* __restrict__ gam,
                                                        const float* __restrict__ bet,
                                                        const float* __restrict__ pw,
                                                        const float* __restrict__ pbias,
                                                        const float* __restrict__ mask,
                                                        unsigned short* __restrict__ out,
                                                        float* __restrict__ alpha) {
  const long row = blockIdx.x;
  const unsigned short* x = in + row * 512;
  float v0 = bf2f(x[threadIdx.x]), v1 = bf2f(x[threadIdx.x + 256]);
  float s = v0 + v1, ss = v0 * v0 + v1 * v1;
  #pragma unroll
  for (int off = 32; off > 0; off >>= 1) {
    s += __shfl_down(s, off, 64);
    ss += __shfl_down(ss, off, 64);
  }
  __shared__ float red[8];
  __shared__ float mv[2];
  __shared__ float pr[4][8];
  int w = threadIdx.x >> 6, ln = threadIdx.x & 63;
  if (ln == 0) { red[w] = s; red[w + 4] = ss; }
  __syncthreads();
  if (threadIdx.x == 0) {
    float S = red[0] + red[1] + red[2] + red[3];
    float SS = red[4] + red[5] + red[6] + red[7];
    float mu = S * (1.f / 512.f);
    float var = SS * (1.f / 512.f) - mu * mu;
    mv[0] = mu;
    mv[1] = rsqrtf(var + 1e-5f);
  }
  __syncthreads();
  float mu = mv[0], rs = mv[1];
  float o0 = (v0 - mu) * rs * gam[threadIdx.x] + bet[threadIdx.x];
  float o1 = (v1 - mu) * rs * gam[threadIdx.x + 256] + bet[threadIdx.x + 256];
  out[row * 512 + threadIdx.x] = bf16r(o0);
  out[row * 512 + threadIdx.x + 256] = bf16r(o1);
  // fused alpha: p[k] = sum_d t[row][d] * pw[d][k]
  float p[8];
  const float* w0 = pw + threadIdx.x * 8;
  const float* w1 = pw + (threadIdx.x + 256) * 8;
  #pragma unroll
  for (int k = 0; k < 8; k++) p[k] = o0 * w0[k] + o1 * w1[k];
  #pragma unroll
  for (int off = 32; off > 0; off >>= 1)
    #pragma unroll
    for (int k = 0; k < 8; k++) p[k] += __shfl_down(p[k], off, 64);
  if (ln == 0)
    #pragma unroll
    for (int k = 0; k < 8; k++) pr[w][k] = p[k];
  __syncthreads();
  if (threadIdx.x < 8) {
    float a = pr[0][threadIdx.x] + pr[1][threadIdx.x] + pr[2][threadIdx.x] + pr[3][threadIdx.x]
              + pbias[threadIdx.x];
    a = a < 0.f ? 0.01f * a : a;
    alpha[row * 8 + threadIdx.x] = a + mask[row] * (-1e16f);
  }
}

// ------- pool with fused per-batch softmax stats (redundant per block) -------
__global__ __launch_bounds__(256) void pool_kernel(const unsigned short* __restrict__ h,
                                                   const float* __restrict__ alpha,
                                                   float* __restrict__ partial) {
  int b = blockIdx.x >> 3, sc = blockIdx.x & 7;
  int w = threadIdx.x >> 6, ln = threadIdx.x & 63;
  __shared__ float red[4][8];
  __shared__ float Ms[8], Ss[8];
  __shared__ float wb[256];
  const float* ab = alpha + (long)b * 2048 * 8;
  float m[8];
  #pragma unroll
  for (int k = 0; k < 8; k++) m[k] = -1e38f;
  for (int s = threadIdx.x; s < 2048; s += 256) {
    const float* a = ab + (long)s * 8;
    #pragma unroll
    for (int k = 0; k < 8; k++) m[k] = fmaxf(m[k], a[k]);
  }
  #pragma unroll
  for (int off = 32; off > 0; off >>= 1)
    #pragma unroll
    for (int k = 0; k < 8; k++) m[k] = fmaxf(m[k], __shfl_down(m[k], off, 64));
  if (ln == 0)
    #pragma unroll
    for (int k = 0; k < 8; k++) red[w][k] = m[k];
  __syncthreads();
  if (threadIdx.x < 8)
    Ms[threadIdx.x] = fmaxf(fmaxf(red[0][threadIdx.x], red[1][threadIdx.x]),
                            fmaxf(red[2][threadIdx.x], red[3][threadIdx.x]));
  __syncthreads();
  float sm[8];
  #pragma unroll
  for (int k = 0; k < 8; k++) sm[k] = 0.f;
  for (int s = threadIdx.x; s < 2048; s += 256) {
    const float* a = ab + (long)s * 8;
    #pragma unroll
    for (int k = 0; k < 8; k++) sm[k] += __expf(a[k] - Ms[k]);
  }
  #pragma unroll
  for (int off = 32; off > 0; off >>= 1)
    #pragma unroll
    for (int k = 0; k < 8; k++) sm[k] += __shfl_down(sm[k], off, 64);
  __syncthreads();
  if (ln == 0)
    #pragma unroll
    for (int k = 0; k < 8; k++) red[w][k] = sm[k];
  __syncthreads();
  if (threadIdx.x < 8)
    Ss[threadIdx.x] = red[0][threadIdx.x] + red[1][threadIdx.x] +
                      red[2][threadIdx.x] + red[3][threadIdx.x];
  __syncthreads();
  int s0 = sc * 256;
  {
    const float* a = ab + (long)(s0 + threadIdx.x) * 8;
    float wsum = 0.f;
    #pragma unroll
    for (int ph = 0; ph < 8; ph++) wsum += __expf(a[ph] - Ms[ph]) / Ss[ph];
    wb[threadIdx.x] = wsum;
  }
  __syncthreads();
  float a0 = 0.f, a1 = 0.f;
  const unsigned short* hb = h + ((long)b * 2048 + s0) * 512;
  for (int i = 0; i < 256; i++) {
    float wv = wb[i];
    a0 += wv * bf2f(hb[(long)i * 512 + threadIdx.x]);
    a1 += wv * bf2f(hb[(long)i * 512 + threadIdx.x + 256]);
  }
  partial[(long)blockIdx.x * 512 + threadIdx.x] = a0;
  partial[(long)blockIdx.x * 512 + threadIdx.x + 256] = a1;
}

__global__ __launch_bounds__(256) void pool_final(const float* __restrict__ partial,
                                                  float* __restrict__ out) {
  int b = blockIdx.x;
  float a0 = 0.f, a1 = 0.f;
  #pragma unroll
  for (int sc = 0; sc < 8; sc++) {
    a0 += partial[(long)(b * 8 + sc) * 512 + threadIdx.x];
    a1 += partial[(long)(b * 8 + sc) * 512 + threadIdx.x + 256];
  }
  out[b * 512 + threadIdx.x] = a0;
  out[b * 512 + threadIdx.x + 256] = a1;
}

// -----------------------------------------------------------------------------
extern "C" void kernel_launch(void* const* d_in, const int* in_sizes, int n_in,
                              void* d_out, int out_size, void* d_ws, size_t ws_size,
                              hipStream_t stream) {
  (void)in_sizes; (void)n_in; (void)out_size;
  if (ws_size < 92274688UL) return;  // need ~88MB scratch

  const float* x    = (const float*)d_in[0];
  const float* mask = (const float*)d_in[1];
  const float* q1w = (const float*)d_in[2];  const float* q1b = (const float*)d_in[3];
  const float* k1w = (const float*)d_in[4];  const float* k1b = (const float*)d_in[5];
  const float* v1w = (const float*)d_in[6];  const float* v1b = (const float*)d_in[7];
  const float* o1w = (const float*)d_in[8];  const float* o1b = (const float*)d_in[9];
  const float* q2w = (const float*)d_in[10]; const float* q2b = (const float*)d_in[11];
  const float* k2w = (const float*)d_in[12]; const float* k2b = (const float*)d_in[13];
  const float* v2w = (const float*)d_in[14]; const float* v2b = (const float*)d_in[15];
  const float* o2w = (const float*)d_in[16]; const float* o2b = (const float*)d_in[17];
  const float* ln1g = (const float*)d_in[18]; const float* ln1b = (const float*)d_in[19];
  const float* fw1 = (const float*)d_in[20]; const float* fb1 = (const float*)d_in[21];
  const float* fw2 = (const float*)d_in[22]; const float* fb2 = (const float*)d_in[23];
  const float* ln2g = (const float*)d_in[24]; const float* ln2b = (const float*)d_in[25];
  const float* poolw = (const float*)d_in[26]; const float* poolb = (const float*)d_in[27];

  char* ws = (char*)d_ws;
  unsigned short* Wt  = (unsigned short*)(ws + 0);          // 10 x 512x512 bf16 (5MB)
  float* qb1          = (float*)(ws + 5242880);
  float* qb2          = (float*)(ws + 5249024);
  float* alpha        = (float*)(ws + 5255424);             // 256KB
  float* partial      = (float*)(ws + 5517568);             // 64KB
  unsigned short* qkv = (unsigned short*)(ws + 8388608);    // [8192][1536] bf16 (24MB)
  unsigned short* vt  = (unsigned short*)(ws + 33554432);   // [32][64][2048] bf16 (8MB)
  unsigned short* ao  = (unsigned short*)(ws + 41943040);   // [8192][512] bf16 (8MB)
  unsigned short* tb  = (unsigned short*)(ws + 50331648);   // [8192][512] bf16 (8MB)
  unsigned short* xn  = (unsigned short*)(ws + 67108864);   // [8192][512] bf16 (8MB)
  unsigned short* h1  = (unsigned short*)(ws + 75497472);   // (8MB)
  unsigned short* f   = (unsigned short*)(ws + 83886080);   // (8MB)
  unsigned short* h2  = xn;                                 // xn dead by then

  PrepArgs pa;
  pa.w[0] = q1w; pa.w[1] = k1w; pa.w[2] = v1w; pa.w[3] = o1w; pa.w[4] = fw1;
  pa.w[5] = fw2; pa.w[6] = q2w; pa.w[7] = k2w; pa.w[8] = v2w; pa.w[9] = o2w;
  pa.b1[0] = q1b; pa.b1[1] = k1b; pa.b1[2] = v1b;
  pa.b2[0] = q2b; pa.b2[1] = k2b; pa.b2[2] = v2b;

  prep_l2norm_kernel<<<8832, 256, 0, stream>>>(pa, Wt, qb1, qb2, x, xn);

  // layer 1 (QKV GEMM writes V directly transposed into vt)
  gemm_bt<3><<<dim3(64, 12), 256, 0, stream>>>(xn, Wt, qb1, qkv, 512, 1536, vt);
  attn_kernel<<<dim3(16, 32), 256, 0, stream>>>(qkv, vt, mask, ao);
  gemm_bt64<1><<<dim3(64, 8), 256, 0, stream>>>(ao, Wt + 3L * 512 * 512, o1b, tb, 512, 512);
  ln_kernel<<<8192, 256, 0, stream>>>(tb, ln1g, ln1b, h1);
  gemm_bt64<2><<<dim3(64, 8), 256, 0, stream>>>(h1, Wt + 4L * 512 * 512, fb1, f, 512, 512);
  gemm_bt64<1><<<dim3(64, 8), 256, 0, stream>>>(f, Wt + 5L * 512 * 512, fb2, h2, 512, 512);

  // layer 2
  gemm_bt<3><<<dim3(64, 12), 256, 0, stream>>>(h2, Wt + 6L * 512 * 512, qb2, qkv, 512, 1536, vt);
  attn_kernel<<<dim3(16, 32), 256, 0, stream>>>(qkv, vt, mask, ao);
  gemm_bt64<1><<<dim3(64, 8), 256, 0, stream>>>(ao, Wt + 9L * 512 * 512, o2b, tb, 512, 512);
  ln2_alpha_kernel<<<8192, 256, 0, stream>>>(tb, ln2g, ln2b, poolw, poolb, mask, tb, alpha);

  // pooling (stats fused into pool_kernel)
  pool_kernel<<<32, 256, 0, stream>>>(tb, alpha, partial);
  pool_final<<<4, 256, 0, stream>>>(partial, (float*)d_out);
}

// Round 17
// 282.557 us; speedup vs baseline: 1.0606x; 1.0606x over previous
//
#include <hip/hip_runtime.h>
#include <hip/hip_bf16.h>
#include <stdint.h>

#define DEVI __device__ __forceinline__

typedef float f32x4 __attribute__((ext_vector_type(4)));
typedef float f32x16 __attribute__((ext_vector_type(16)));
typedef short bf16x8 __attribute__((ext_vector_type(8)));

typedef __attribute__((address_space(3))) unsigned int as3_u32;
typedef __attribute__((address_space(1))) unsigned int as1_u32;

DEVI void gload16(const void* g, void* l) {
  __builtin_amdgcn_global_load_lds((const as1_u32*)g, (as3_u32*)l, 16, 0, 0);
}

DEVI unsigned short bf16r(float f) {
  union { float f; unsigned int u; } v; v.f = f;
  unsigned int u = v.u;
  return (unsigned short)((u + 0x7FFFu + ((u >> 16) & 1u)) >> 16);
}

DEVI float bf2f(unsigned short u) {
  unsigned int x = ((unsigned int)u) << 16;
  union { unsigned int u; float f; } v; v.u = x;
  return v.f;
}

DEVI unsigned int pkbf16(float a, float b) {
  __hip_bfloat162 h = __float22bfloat162_rn(make_float2(a, b));
  return *(unsigned int*)&h;
}

// ------- merged: weight prep (blocks 0..639) + x l2norm (blocks 640..8831) ---
struct PrepArgs {
  const float* w[10];
  const float* b1[3];
  const float* b2[3];
};

__global__ __launch_bounds__(256) void prep_l2norm_kernel(PrepArgs pa, unsigned short* wt,
                                                          float* qb1, float* qb2,
                                                          const float* __restrict__ x,
                                                          unsigned short* __restrict__ xn) {
  const int bid = blockIdx.x;
  if (bid < 640) {
    __shared__ float lt[64][65];
    const int slot = bid >> 6, r = bid & 63;
    const int n0 = (r & 7) * 64, k0 = (r >> 3) * 64;
    const float* W = pa.w[slot];
    for (int it = 0; it < 16; it++) {
      int idx = it * 256 + threadIdx.x;
      int kr = idx >> 6, nc = idx & 63;
      lt[kr][nc] = W[(long)(k0 + kr) * 512 + n0 + nc];
    }
    __syncthreads();
    unsigned short* dst = wt + (long)slot * 512 * 512;
    for (int it = 0; it < 16; it++) {
      int idx = it * 256 + threadIdx.x;
      int nr = idx >> 6, kc = idx & 63;
      dst[(long)(n0 + nr) * 512 + k0 + kc] = bf16r(lt[kc][nr]);
    }
    if (r == 0) {
      if (slot < 3) {
        for (int i = threadIdx.x; i < 512; i += 256) qb1[slot * 512 + i] = pa.b1[slot][i];
      } else if (slot >= 6 && slot < 9) {
        for (int i = threadIdx.x; i < 512; i += 256) qb2[(slot - 6) * 512 + i] = pa.b2[slot - 6][i];
      }
    }
  } else {
    const long row = bid - 640;
    const float* xr = x + row * 512;
    float v0 = xr[threadIdx.x], v1 = xr[threadIdx.x + 256];
    float ss = v0 * v0 + v1 * v1;
    #pragma unroll
    for (int off = 32; off > 0; off >>= 1) ss += __shfl_down(ss, off, 64);
    __shared__ float red[4];
    __shared__ float sc[1];
    int w = threadIdx.x >> 6, ln = threadIdx.x & 63;
    if (ln == 0) red[w] = ss;
    __syncthreads();
    if (threadIdx.x == 0) {
      float S = red[0] + red[1] + red[2] + red[3];
      sc[0] = 1.0f / fmaxf(sqrtf(S), 1e-12f);
    }
    __syncthreads();
    float s = sc[0];
    xn[row * 512 + threadIdx.x] = bf16r(v0 * s);
    xn[row * 512 + threadIdx.x + 256] = bf16r(v1 * s);
  }
}

// ---------------- GEMM 128x128: C = A x Bt^T + bias --------------------------
// EPI: 1 = bf16 out, 2 = bf16 out + relu,
//      3 = bf16 out; cols >=1024 are V -> written transposed into vtout
template <int EPI>
__global__ __launch_bounds__(256) void gemm_bt(const unsigned short* __restrict__ A,
                                               const unsigned short* __restrict__ Bt,
                                               const float* __restrict__ bias,
                                               void* __restrict__ Cv, int K, int N,
                                               unsigned short* __restrict__ vtout) {
  __shared__ unsigned short ldsA[128 * 64];
  __shared__ unsigned short ldsB[128 * 64];
  const int tid = threadIdx.x, w = tid >> 6, ln = tid & 63;
  const int bm = blockIdx.x, bn = blockIdx.y;
  const int wm = (w >> 1) * 64, wn = (w & 1) * 64;
  const f32x4 zf = {0.f, 0.f, 0.f, 0.f};
  f32x4 acc[4][4];
  #pragma unroll
  for (int i = 0; i < 4; i++)
    #pragma unroll
    for (int j = 0; j < 4; j++) acc[i][j] = zf;
  const int r8 = ln >> 3, s8 = ln & 7;
  for (int kt = 0; kt < K; kt += 64) {
    #pragma unroll
    for (int i = 0; i < 4; i++) {
      int row = w * 32 + i * 8 + r8;
      gload16(A + (long)(bm * 128 + row) * K + kt + s8 * 8, &ldsA[(w * 32 + i * 8) * 64]);
      gload16(Bt + (long)(bn * 128 + row) * K + kt + s8 * 8, &ldsB[(w * 32 + i * 8) * 64]);
    }
    __syncthreads();
    #pragma unroll
    for (int kk = 0; kk < 2; kk++) {
      bf16x8 af[4], bfr[4];
      #pragma unroll
      for (int mf = 0; mf < 4; mf++) {
        int row = wm + mf * 16 + (ln & 15);
        af[mf] = *(const bf16x8*)&ldsA[row * 64 + kk * 32 + (ln >> 4) * 8];
      }
      #pragma unroll
      for (int nf = 0; nf < 4; nf++) {
        int row = wn + nf * 16 + (ln & 15);
        bfr[nf] = *(const bf16x8*)&ldsB[row * 64 + kk * 32 + (ln >> 4) * 8];
      }
      #pragma unroll
      for (int mf = 0; mf < 4; mf++)
        #pragma unroll
        for (int nf = 0; nf < 4; nf++)
          acc[mf][nf] = __builtin_amdgcn_mfma_f32_16x16x32_bf16(af[mf], bfr[nf], acc[mf][nf], 0, 0, 0);
    }
    __syncthreads();
  }
  const int g = ln >> 4, c = ln & 15;
  #pragma unroll
  for (int mf = 0; mf < 4; mf++) {
    #pragma unroll
    for (int nf = 0; nf < 4; nf++) {
      int col = bn * 128 + wn + nf * 16 + c;
      float bv = bias[col];
      if (EPI == 3 && col >= 1024) {
        long row0 = bm * 128 + wm + mf * 16 + g * 4;
        int b = (int)(row0 >> 11), s = (int)(row0 & 2047);
        int vc = col - 1024, h = vc >> 6, hd = vc & 63;
        ushort4 o;
        o.x = bf16r(acc[mf][nf][0] + bv);
        o.y = bf16r(acc[mf][nf][1] + bv);
        o.z = bf16r(acc[mf][nf][2] + bv);
        o.w = bf16r(acc[mf][nf][3] + bv);
        *(ushort4*)(vtout + ((long)((b * 8 + h) * 64 + hd)) * 2048 + s) = o;
      } else {
        #pragma unroll
        for (int j = 0; j < 4; j++) {
          long row = bm * 128 + wm + mf * 16 + g * 4 + j;
          float v = acc[mf][nf][j] + bv;
          if (EPI == 2) v = v > 0.f ? v : 0.f;
          ((unsigned short*)Cv)[row * N + col] = bf16r(v);
        }
      }
    }
  }
}

// ---------------- GEMM 64x64 tile (N=512 chains: 1024 blocks, 4/CU) ----------
template <int EPI>  // 1 = bf16 out, 2 = bf16 + relu
__global__ __launch_bounds__(256) void gemm64(const unsigned short* __restrict__ A,
                                              const unsigned short* __restrict__ Bt,
                                              const float* __restrict__ bias,
                                              void* __restrict__ Cv, int K, int N) {
  __shared__ unsigned short ldsA[64 * 64];
  __shared__ unsigned short ldsB[64 * 64];
  const int tid = threadIdx.x, w = tid >> 6, ln = tid & 63;
  const int bm = blockIdx.x, bn = blockIdx.y;
  const int wm = (w >> 1) * 32, wn = (w & 1) * 32;
  const f32x4 zf = {0.f, 0.f, 0.f, 0.f};
  f32x4 acc[2][2];
  #pragma unroll
  for (int i = 0; i < 2; i++)
    #pragma unroll
    for (int j = 0; j < 2; j++) acc[i][j] = zf;
  const int r8 = ln >> 3, s8 = ln & 7;
  for (int kt = 0; kt < K; kt += 64) {
    #pragma unroll
    for (int u = 0; u < 4; u++) {
      int jj = w * 4 + u;
      if (jj < 8) {
        gload16(A + (long)(bm * 64 + jj * 8 + r8) * K + kt + s8 * 8, &ldsA[jj * 512]);
      } else {
        int jb = jj - 8;
        gload16(Bt + (long)(bn * 64 + jb * 8 + r8) * K + kt + s8 * 8, &ldsB[jb * 512]);
      }
    }
    __syncthreads();
    #pragma unroll
    for (int kk = 0; kk < 2; kk++) {
      bf16x8 af[2], bfr[2];
      #pragma unroll
      for (int mf = 0; mf < 2; mf++)
        af[mf] = *(const bf16x8*)&ldsA[(wm + mf * 16 + (ln & 15)) * 64 + kk * 32 + (ln >> 4) * 8];
      #pragma unroll
      for (int nf = 0; nf < 2; nf++)
        bfr[nf] = *(const bf16x8*)&ldsB[(wn + nf * 16 + (ln & 15)) * 64 + kk * 32 + (ln >> 4) * 8];
      #pragma unroll
      for (int mf = 0; mf < 2; mf++)
        #pragma unroll
        for (int nf = 0; nf < 2; nf++)
          acc[mf][nf] = __builtin_amdgcn_mfma_f32_16x16x32_bf16(af[mf], bfr[nf], acc[mf][nf], 0, 0, 0);
    }
    __syncthreads();
  }
  const int g = ln >> 4, c = ln & 15;
  #pragma unroll
  for (int mf = 0; mf < 2; mf++) {
    #pragma unroll
    for (int nf = 0; nf < 2; nf++) {
      int col = bn * 64 + wn + nf * 16 + c;
      float bv = bias[col];
      #pragma unroll
      for (int j = 0; j < 4; j++) {
        long row = bm * 64 + wm + mf * 16 + g * 4 + j;
        float v = acc[mf][nf][j] + bv;
        if (EPI == 2) v = v > 0.f ? v : 0.f;
        ((unsigned short*)Cv)[row * N + col] = bf16r(v);
      }
    }
  }
}

// ---------------- fused attention, FULL-K, 32x32 MFMA, in-register P ---------
// Round-13 structure (measured optimum): 2 buffers, 2 barriers/iter, no setprio.
__global__ __launch_bounds__(256, 4) void attn_kernel(
    const unsigned short* __restrict__ qkv,
    const unsigned short* __restrict__ vt,
    const float* __restrict__ mask,
    unsigned short* __restrict__ ao) {
  const int tid = threadIdx.x, w = tid >> 6, ln = tid & 63;
  const int lo = ln & 31, hi = ln >> 5;
  // XCD-aware bijective swizzle (512 = 8 x 64)
  const int bid = blockIdx.x + 16 * blockIdx.y;
  const int swz = (bid & 7) * 64 + (bid >> 3);
  const int qb = swz & 15, bh = swz >> 4;
  const int b = bh >> 3, h = bh & 7;
  const int q0 = qb * 128 + w * 32;
  const unsigned short* qp = qkv + (long)(b * 2048) * 1536 + h * 64;
  const unsigned short* kp = qp + 512;
  const unsigned short* vtp = vt + (long)bh * 64 * 2048;
  const float* mp = mask + b * 2048;

  __shared__ unsigned short sbuf[2][4096];   // 8KB per buffer
  __shared__ float mbuf[2048];
  __shared__ int mflag;

  {
    float acc = 0.f;
    #pragma unroll
    for (int i = 0; i < 8; i++) {
      float mv = mp[i * 256 + tid];
      mbuf[i * 256 + tid] = mv;
      acc += fabsf(mv);
    }
    if (tid == 0) mflag = 0;
    __syncthreads();
    if (acc != 0.f) mflag = 1;
    __syncthreads();
  }
  const bool anymask = (mflag != 0);

  const int jj0 = w * 2;
  const char *src0, *src1;
  long step;
  if (w < 2) {
    int r0 = jj0 * 8 + (ln >> 3), r1 = r0 + 8, s = ln & 7;
    src0 = (const char*)kp + 2L * ((long)r0 * 1536 + ((s ^ (r0 & 7)) * 8));
    src1 = (const char*)kp + 2L * ((long)r1 * 1536 + ((s ^ (r1 & 7)) * 8));
    step = 32L * 1536 * 2;
  } else {
    int j0 = (w - 2) * 2;
    int r0 = j0 * 16 + (ln >> 2), r1 = r0 + 16, s = ln & 3;
    src0 = (const char*)vtp + 2L * ((long)r0 * 2048 + ((s ^ ((r0 >> 1) & 3)) * 8));
    src1 = (const char*)vtp + 2L * ((long)r1 * 2048 + ((s ^ ((r1 >> 1) & 3)) * 8));
    step = 64;
  }
  unsigned short* const d0a = &sbuf[0][jj0 * 512];
  unsigned short* const d0b = d0a + 512;
  unsigned short* const d1a = &sbuf[1][jj0 * 512];
  unsigned short* const d1b = d1a + 512;

  int koffe[4];
  #pragma unroll
  for (int t = 0; t < 4; t++)
    koffe[t] = lo * 64 + (((t * 2 + hi) ^ (lo & 7)) * 8);
  int voffe[4];
  #pragma unroll
  for (int stt = 0; stt < 2; stt++)
    #pragma unroll
    for (int tau = 0; tau < 2; tau++) {
      int vr = tau * 32 + lo;
      voffe[stt * 2 + tau] = 2048 + vr * 32 + ((((stt * 2 + hi) ^ ((vr >> 1) & 3))) * 8);
    }

  bf16x8 qf[4];
  #pragma unroll
  for (int t = 0; t < 4; t++)
    qf[t] = *(const bf16x8*)(qp + (long)(q0 + lo) * 1536 + t * 16 + hi * 8);

  f32x16 oacc[2];
  #pragma unroll
  for (int t = 0; t < 2; t++)
    #pragma unroll
    for (int r = 0; r < 16; r++) oacc[t][r] = 0.f;
  float lsum = 0.f;
  const f32x16 zf16 = oacc[0];
  const float SC = 0.18033688011112042f;  // 0.125 * log2(e)

  gload16(src0, d0a);
  gload16(src1, d0b);
  src0 += step; src1 += step;

#define ATTN_BODY(CURB, DA, DB, ITOFF, STAGE_NEXT)                              \
  {                                                                             \
    if (STAGE_NEXT) {                                                           \
      gload16(src0, DA);                                                        \
      gload16(src1, DB);                                                        \
      src0 += step; src1 += step;                                               \
      asm volatile("s_waitcnt vmcnt(2)" ::: "memory");                          \
    } else {                                                                    \
      asm volatile("s_waitcnt vmcnt(0)" ::: "memory");                          \
    }                                                                           \
    __builtin_amdgcn_s_barrier();                                               \
    __builtin_amdgcn_sched_barrier(0);                                          \
    f32x16 sacc = zf16;                                                         \
    _Pragma("unroll")                                                           \
    for (int t = 0; t < 4; t++) {                                               \
      bf16x8 kf = *(const bf16x8*)&sbuf[CURB][koffe[t]];                        \
      sacc = __builtin_amdgcn_mfma_f32_32x32x16_bf16(kf, qf[t], sacc, 0, 0, 0); \
    }                                                                           \
    float e[16];                                                                \
    _Pragma("unroll")                                                           \
    for (int r = 0; r < 16; r++) e[r] = sacc[r] * SC;                           \
    if (anymask) {                                                              \
      float mval = mbuf[(ITOFF) + lo];                                          \
      _Pragma("unroll")                                                         \
      for (int r = 0; r < 16; r++)                                              \
        e[r] -= 1.4426950408889634e30f *                                        \
                __shfl(mval, (r & 3) + 8 * (r >> 2) + 4 * hi, 64);              \
    }                                                                           \
    _Pragma("unroll")                                                           \
    for (int r = 0; r < 16; r++) e[r] = __builtin_amdgcn_exp2f(e[r]);           \
    _Pragma("unroll")                                                           \
    for (int r = 0; r < 16; r++) lsum += e[r];                                  \
    unsigned int cv[8];                                                         \
    _Pragma("unroll")                                                           \
    for (int i = 0; i < 8; i++) cv[i] = pkbf16(e[2 * i], e[2 * i + 1]);         \
    _Pragma("unroll")                                                           \
    for (int stt = 0; stt < 2; stt++) {                                         \
      unsigned int pf[4];                                                       \
      {                                                                         \
        auto r0_ = __builtin_amdgcn_permlane32_swap(cv[stt * 4 + 0],            \
                                                    cv[stt * 4 + 2], false, false); \
        auto r1_ = __builtin_amdgcn_permlane32_swap(cv[stt * 4 + 1],            \
                                                    cv[stt * 4 + 3], false, false); \
        pf[0] = r0_[0]; pf[1] = r1_[0]; pf[2] = r0_[1]; pf[3] = r1_[1];         \
      }                                                                         \
      bf16x8 pfr = *(const bf16x8*)pf;                                          \
      _Pragma("unroll")                                                         \
      for (int tau = 0; tau < 2; tau++) {                                       \
        bf16x8 vf = *(const bf16x8*)&sbuf[CURB][voffe[stt * 2 + tau]];          \
        oacc[tau] = __builtin_amdgcn_mfma_f32_32x32x16_bf16(vf, pfr, oacc[tau], 0, 0, 0); \
      }                                                                         \
    }                                                                           \
    __builtin_amdgcn_sched_barrier(0);                                          \
    __builtin_amdgcn_s_barrier();                                               \
  }

  for (int it2 = 0; it2 < 32; it2++) {
    ATTN_BODY(0, d1a, d1b, it2 * 64, 1)
    ATTN_BODY(1, d0a, d0b, it2 * 64 + 32, (it2 < 31))
  }
#undef ATTN_BODY

  lsum += __shfl_xor(lsum, 32, 64);
  const float inv = 1.f / lsum;
  unsigned short* ob = ao + ((long)(b * 2048) + q0 + lo) * 512 + h * 64;
  #pragma unroll
  for (int tau = 0; tau < 2; tau++) {
    #pragma unroll
    for (int j = 0; j < 4; j++) {
      ushort4 o;
      o.x = bf16r(oacc[tau][4 * j + 0] * inv);
      o.y = bf16r(oacc[tau][4 * j + 1] * inv);
      o.z = bf16r(oacc[tau][4 * j + 2] * inv);
      o.w = bf16r(oacc[tau][4 * j + 3] * inv);
      *(ushort4*)(ob + tau * 32 + j * 8 + hi * 4) = o;
    }
  }
}

// ---------------- layernorm rows, bf16 in -> bf16 out ------------------------
__global__ __launch_bounds__(256) void ln_kernel(const unsigned short* __restrict__ in,
                                                 const float* __restrict__ gam,
                                                 const float* __restrict__ bet,
                                                 unsigned short* __restrict__ out) {
  const long row = blockIdx.x;
  const unsigned short* x = in + row * 512;
  float v0 = bf2f(x[threadIdx.x]), v1 = bf2f(x[threadIdx.x + 256]);
  float s = v0 + v1, ss = v0 * v0 + v1 * v1;
  #pragma unroll
  for (int off = 32; off > 0; off >>= 1) {
    s += __shfl_down(s, off, 64);
    ss += __shfl_down(ss, off, 64);
  }
  __shared__ float red[8];
  __shared__ float mv[2];
  int w = threadIdx.x >> 6, ln = threadIdx.x & 63;
  if (ln == 0) { red[w] = s; red[w + 4] = ss; }
  __syncthreads();
  if (threadIdx.x == 0) {
    float S = red[0] + red[1] + red[2] + red[3];
    float SS = red[4] + red[5] + red[6] + red[7];
    float mu = S * (1.f / 512.f);
    float var = SS * (1.f / 512.f) - mu * mu;
    mv[0] = mu;
    mv[1] = rsqrtf(var + 1e-5f);
  }
  __syncthreads();
  float mu = mv[0], rs = mv[1];
  float o0 = (v0 - mu) * rs * gam[threadIdx.x] + bet[threadIdx.x];
  float o1 = (v1 - mu) * rs * gam[threadIdx.x + 256] + bet[threadIdx.x + 256];
  out[row * 512 + threadIdx.x] = bf16r(o0);
  out[row * 512 + threadIdx.x + 256] = bf16r(o1);
}

// ---------------- LN2 (bf16 in/out) + fused alpha ----------------------------
__global__ __launch_bounds__(256) void ln2_alpha_kernel(const unsigned short* __restrict__ in,
                                                        const float* __restrict__ gam,
                                                        const float* __restrict__ bet,
                                                        const float* __restrict__ pw,
                                                        const float* __restrict__ pbias,
                                                        const float* __restrict__ mask,
                                                        unsigned short* __restrict__ out,
                                                        float* __restrict__ alpha) {
  const long row = blockIdx.x;
  const unsigned short* x = in + row * 512;
  float v0 = bf2f(x[threadIdx.x]), v1 = bf2f(x[threadIdx.x + 256]);
  float s = v0 + v1, ss = v0 * v0 + v1 * v1;
  #pragma unroll
  for (int off = 32; off > 0; off >>= 1) {
    s += __shfl_down(s, off, 64);
    ss += __shfl_down(ss, off, 64);
  }
  __shared__ float red[8];
  __shared__ float mv[2];
  __shared__ float pr[4][8];
  int w = threadIdx.x >> 6, ln = threadIdx.x & 63;
  if (ln == 0) { red[w] = s; red[w + 4] = ss; }
  __syncthreads();
  if (threadIdx.x == 0) {
    float S = red[0] + red[1] + red[2] + red[3];
    float SS = red[4] + red[5] + red[6] + red[7];
    float mu = S * (1.f / 512.f);
    float var = SS * (1.f / 512.f) - mu * mu;
    mv[0] = mu;
    mv[1] = rsqrtf(var + 1e-5f);
  }
  __syncthreads();
  float mu = mv[0], rs = mv[1];
  float o0 = (v0 - mu) * rs * gam[threadIdx.x] + bet[threadIdx.x];
  float o1 = (v1 - mu) * rs * gam[threadIdx.x + 256] + bet[threadIdx.x + 256];
  out[row * 512 + threadIdx.x] = bf16r(o0);
  out[row * 512 + threadIdx.x + 256] = bf16r(o1);
  // fused alpha: p[k] = sum_d t[row][d] * pw[d][k]
  float p[8];
  const float* w0 = pw + threadIdx.x * 8;
  const float* w1 = pw + (threadIdx.x + 256) * 8;
  #pragma unroll
  for (int k = 0; k < 8; k++) p[k] = o0 * w0[k] + o1 * w1[k];
  #pragma unroll
  for (int off = 32; off > 0; off >>= 1)
    #pragma unroll
    for (int k = 0; k < 8; k++) p[k] += __shfl_down(p[k], off, 64);
  if (ln == 0)
    #pragma unroll
    for (int k = 0; k < 8; k++) pr[w][k] = p[k];
  __syncthreads();
  if (threadIdx.x < 8) {
    float a = pr[0][threadIdx.x] + pr[1][threadIdx.x] + pr[2][threadIdx.x] + pr[3][threadIdx.x]
              + pbias[threadIdx.x];
    a = a < 0.f ? 0.01f * a : a;
    alpha[row * 8 + threadIdx.x] = a + mask[row] * (-1e16f);
  }
}

// ------- pool with fused per-batch softmax stats (redundant per block) -------
__global__ __launch_bounds__(256) void pool_kernel(const unsigned short* __restrict__ h,
                                                   const float* __restrict__ alpha,
                                                   float* __restrict__ partial) {
  int b = blockIdx.x >> 3, sc = blockIdx.x & 7;
  int w = threadIdx.x >> 6, ln = threadIdx.x & 63;
  __shared__ float red[4][8];
  __shared__ float Ms[8], Ss[8];
  __shared__ float wb[256];
  const float* ab = alpha + (long)b * 2048 * 8;
  float m[8];
  #pragma unroll
  for (int k = 0; k < 8; k++) m[k] = -1e38f;
  for (int s = threadIdx.x; s < 2048; s += 256) {
    const float* a = ab + (long)s * 8;
    #pragma unroll
    for (int k = 0; k < 8; k++) m[k] = fmaxf(m[k], a[k]);
  }
  #pragma unroll
  for (int off = 32; off > 0; off >>= 1)
    #pragma unroll
    for (int k = 0; k < 8; k++) m[k] = fmaxf(m[k], __shfl_down(m[k], off, 64));
  if (ln == 0)
    #pragma unroll
    for (int k = 0; k < 8; k++) red[w][k] = m[k];
  __syncthreads();
  if (threadIdx.x < 8)
    Ms[threadIdx.x] = fmaxf(fmaxf(red[0][threadIdx.x], red[1][threadIdx.x]),
                            fmaxf(red[2][threadIdx.x], red[3][threadIdx.x]));
  __syncthreads();
  float sm[8];
  #pragma unroll
  for (int k = 0; k < 8; k++) sm[k] = 0.f;
  for (int s = threadIdx.x; s < 2048; s += 256) {
    const float* a = ab + (long)s * 8;
    #pragma unroll
    for (int k = 0; k < 8; k++) sm[k] += __expf(a[k] - Ms[k]);
  }
  #pragma unroll
  for (int off = 32; off > 0; off >>= 1)
    #pragma unroll
    for (int k = 0; k < 8; k++) sm[k] += __shfl_down(sm[k], off, 64);
  __syncthreads();
  if (ln == 0)
    #pragma unroll
    for (int k = 0; k < 8; k++) red[w][k] = sm[k];
  __syncthreads();
  if (threadIdx.x < 8)
    Ss[threadIdx.x] = red[0][threadIdx.x] + red[1][threadIdx.x] +
                      red[2][threadIdx.x] + red[3][threadIdx.x];
  __syncthreads();
  int s0 = sc * 256;
  {
    const float* a = ab + (long)(s0 + threadIdx.x) * 8;
    float wsum = 0.f;
    #pragma unroll
    for (int ph = 0; ph < 8; ph++) wsum += __expf(a[ph] - Ms[ph]) / Ss[ph];
    wb[threadIdx.x] = wsum;
  }
  __syncthreads();
  float a0 = 0.f, a1 = 0.f;
  const unsigned short* hb = h + ((long)b * 2048 + s0) * 512;
  for (int i = 0; i < 256; i++) {
    float wv = wb[i];
    a0 += wv * bf2f(hb[(long)i * 512 + threadIdx.x]);
    a1 += wv * bf2f(hb[(long)i * 512 + threadIdx.x + 256]);
  }
  partial[(long)blockIdx.x * 512 + threadIdx.x] = a0;
  partial[(long)blockIdx.x * 512 + threadIdx.x + 256] = a1;
}

__global__ __launch_bounds__(256) void pool_final(const float* __restrict__ partial,
                                                  float* __restrict__ out) {
  int b = blockIdx.x;
  float a0 = 0.f, a1 = 0.f;
  #pragma unroll
  for (int sc = 0; sc < 8; sc++) {
    a0 += partial[(long)(b * 8 + sc) * 512 + threadIdx.x];
    a1 += partial[(long)(b * 8 + sc) * 512 + threadIdx.x + 256];
  }
  out[b * 512 + threadIdx.x] = a0;
  out[b * 512 + threadIdx.x + 256] = a1;
}

// -----------------------------------------------------------------------------
extern "C" void kernel_launch(void* const* d_in, const int* in_sizes, int n_in,
                              void* d_out, int out_size, void* d_ws, size_t ws_size,
                              hipStream_t stream) {
  (void)in_sizes; (void)n_in; (void)out_size;
  if (ws_size < 92274688UL) return;  // need ~88MB scratch

  const float* x    = (const float*)d_in[0];
  const float* mask = (const float*)d_in[1];
  const float* q1w = (const float*)d_in[2];  const float* q1b = (const float*)d_in[3];
  const float* k1w = (const float*)d_in[4];  const float* k1b = (const float*)d_in[5];
  const float* v1w = (const float*)d_in[6];  const float* v1b = (const float*)d_in[7];
  const float* o1w = (const float*)d_in[8];  const float* o1b = (const float*)d_in[9];
  const float* q2w = (const float*)d_in[10]; const float* q2b = (const float*)d_in[11];
  const float* k2w = (const float*)d_in[12]; const float* k2b = (const float*)d_in[13];
  const float* v2w = (const float*)d_in[14]; const float* v2b = (const float*)d_in[15];
  const float* o2w = (const float*)d_in[16]; const float* o2b = (const float*)d_in[17];
  const float* ln1g = (const float*)d_in[18]; const float* ln1b = (const float*)d_in[19];
  const float* fw1 = (const float*)d_in[20]; const float* fb1 = (const float*)d_in[21];
  const float* fw2 = (const float*)d_in[22]; const float* fb2 = (const float*)d_in[23];
  const float* ln2g = (const float*)d_in[24]; const float* ln2b = (const float*)d_in[25];
  const float* poolw = (const float*)d_in[26]; const float* poolb = (const float*)d_in[27];

  char* ws = (char*)d_ws;
  unsigned short* Wt  = (unsigned short*)(ws + 0);          // 10 x 512x512 bf16 (5MB)
  float* qb1          = (float*)(ws + 5242880);
  float* qb2          = (float*)(ws + 5249024);
  float* alpha        = (float*)(ws + 5255424);             // 256KB
  float* partial      = (float*)(ws + 5517568);             // 64KB
  unsigned short* qkv = (unsigned short*)(ws + 8388608);    // [8192][1536] bf16 (24MB)
  unsigned short* vt  = (unsigned short*)(ws + 33554432);   // [32][64][2048] bf16 (8MB)
  unsigned short* ao  = (unsigned short*)(ws + 41943040);   // [8192][512] bf16 (8MB)
  unsigned short* tb  = (unsigned short*)(ws + 50331648);   // [8192][512] bf16 (8MB)
  unsigned short* xn  = (unsigned short*)(ws + 67108864);   // [8192][512] bf16 (8MB)
  unsigned short* h1  = (unsigned short*)(ws + 75497472);   // (8MB)
  unsigned short* f   = (unsigned short*)(ws + 83886080);   // (8MB)
  unsigned short* h2  = xn;                                 // xn dead by then

  PrepArgs pa;
  pa.w[0] = q1w; pa.w[1] = k1w; pa.w[2] = v1w; pa.w[3] = o1w; pa.w[4] = fw1;
  pa.w[5] = fw2; pa.w[6] = q2w; pa.w[7] = k2w; pa.w[8] = v2w; pa.w[9] = o2w;
  pa.b1[0] = q1b; pa.b1[1] = k1b; pa.b1[2] = v1b;
  pa.b2[0] = q2b; pa.b2[1] = k2b; pa.b2[2] = v2b;

  prep_l2norm_kernel<<<8832, 256, 0, stream>>>(pa, Wt, qb1, qb2, x, xn);

  // layer 1 (QKV GEMM writes V directly transposed into vt)
  gemm_bt<3><<<dim3(64, 12), 256, 0, stream>>>(xn, Wt, qb1, qkv, 512, 1536, vt);
  attn_kernel<<<dim3(16, 32), 256, 0, stream>>>(qkv, vt, mask, ao);
  gemm64<1><<<dim3(128, 8), 256, 0, stream>>>(ao, Wt + 3L * 512 * 512, o1b, tb, 512, 512);
  ln_kernel<<<8192, 256, 0, stream>>>(tb, ln1g, ln1b, h1);
  gemm64<2><<<dim3(128, 8), 256, 0, stream>>>(h1, Wt + 4L * 512 * 512, fb1, f, 512, 512);
  gemm64<1><<<dim3(128, 8), 256, 0, stream>>>(f, Wt + 5L * 512 * 512, fb2, h2, 512, 512);

  // layer 2
  gemm_bt<3><<<dim3(64, 12), 256, 0, stream>>>(h2, Wt + 6L * 512 * 512, qb2, qkv, 512, 1536, vt);
  attn_kernel<<<dim3(16, 32), 256, 0, stream>>>(qkv, vt, mask, ao);
  gemm64<1><<<dim3(128, 8), 256, 0, stream>>>(ao, Wt + 9L * 512 * 512, o2b, tb, 512, 512);
  ln2_alpha_kernel<<<8192, 256, 0, stream>>>(tb, ln2g, ln2b, poolw, poolb, mask, tb, alpha);

  // pooling (stats fused into pool_kernel)
  pool_kernel<<<32, 256, 0, stream>>>(tb, alpha, partial);
  pool_final<<<4, 256, 0, stream>>>(partial, (float*)d_out);
}

// Round 18
// 275.665 us; speedup vs baseline: 1.0871x; 1.0250x over previous
//
#include <hip/hip_runtime.h>
#include <hip/hip_bf16.h>
#include <stdint.h>

#define DEVI __device__ __forceinline__

typedef float f32x4 __attribute__((ext_vector_type(4)));
typedef float f32x16 __attribute__((ext_vector_type(16)));
typedef short bf16x8 __attribute__((ext_vector_type(8)));

typedef __attribute__((address_space(3))) unsigned int as3_u32;
typedef __attribute__((address_space(1))) unsigned int as1_u32;

DEVI void gload16(const void* g, void* l) {
  __builtin_amdgcn_global_load_lds((const as1_u32*)g, (as3_u32*)l, 16, 0, 0);
}

DEVI unsigned short bf16r(float f) {
  union { float f; unsigned int u; } v; v.f = f;
  unsigned int u = v.u;
  return (unsigned short)((u + 0x7FFFu + ((u >> 16) & 1u)) >> 16);
}

DEVI float bf2f(unsigned short u) {
  unsigned int x = ((unsigned int)u) << 16;
  union { unsigned int u; float f; } v; v.u = x;
  return v.f;
}

DEVI unsigned int pkbf16(float a, float b) {
  __hip_bfloat162 h = __float22bfloat162_rn(make_float2(a, b));
  return *(unsigned int*)&h;
}

// ------- merged: weight prep (blocks 0..639) + x l2norm (blocks 640..8831) ---
struct PrepArgs {
  const float* w[10];
  const float* b1[3];
  const float* b2[3];
};

__global__ __launch_bounds__(256) void prep_l2norm_kernel(PrepArgs pa, unsigned short* wt,
                                                          float* qb1, float* qb2,
                                                          const float* __restrict__ x,
                                                          unsigned short* __restrict__ xn) {
  const int bid = blockIdx.x;
  if (bid < 640) {
    __shared__ float lt[64][65];
    const int slot = bid >> 6, r = bid & 63;
    const int n0 = (r & 7) * 64, k0 = (r >> 3) * 64;
    const float* W = pa.w[slot];
    for (int it = 0; it < 16; it++) {
      int idx = it * 256 + threadIdx.x;
      int kr = idx >> 6, nc = idx & 63;
      lt[kr][nc] = W[(long)(k0 + kr) * 512 + n0 + nc];
    }
    __syncthreads();
    unsigned short* dst = wt + (long)slot * 512 * 512;
    for (int it = 0; it < 16; it++) {
      int idx = it * 256 + threadIdx.x;
      int nr = idx >> 6, kc = idx & 63;
      dst[(long)(n0 + nr) * 512 + k0 + kc] = bf16r(lt[kc][nr]);
    }
    if (r == 0) {
      if (slot < 3) {
        for (int i = threadIdx.x; i < 512; i += 256) qb1[slot * 512 + i] = pa.b1[slot][i];
      } else if (slot >= 6 && slot < 9) {
        for (int i = threadIdx.x; i < 512; i += 256) qb2[(slot - 6) * 512 + i] = pa.b2[slot - 6][i];
      }
    }
  } else {
    const long row = bid - 640;
    const float* xr = x + row * 512;
    float v0 = xr[threadIdx.x], v1 = xr[threadIdx.x + 256];
    float ss = v0 * v0 + v1 * v1;
    #pragma unroll
    for (int off = 32; off > 0; off >>= 1) ss += __shfl_down(ss, off, 64);
    __shared__ float red[4];
    __shared__ float sc[1];
    int w = threadIdx.x >> 6, ln = threadIdx.x & 63;
    if (ln == 0) red[w] = ss;
    __syncthreads();
    if (threadIdx.x == 0) {
      float S = red[0] + red[1] + red[2] + red[3];
      sc[0] = 1.0f / fmaxf(sqrtf(S), 1e-12f);
    }
    __syncthreads();
    float s = sc[0];
    xn[row * 512 + threadIdx.x] = bf16r(v0 * s);
    xn[row * 512 + threadIdx.x + 256] = bf16r(v1 * s);
  }
}

// ---------------- GEMM 64x64 tile --------------------------------------------
// EPI: 1 = bf16 out, 2 = bf16 + relu,
//      3 = bf16 out; cols >=1024 are V -> written transposed into vtout
template <int EPI>
__global__ __launch_bounds__(256) void gemm64(const unsigned short* __restrict__ A,
                                              const unsigned short* __restrict__ Bt,
                                              const float* __restrict__ bias,
                                              void* __restrict__ Cv, int K, int N,
                                              unsigned short* __restrict__ vtout) {
  __shared__ unsigned short ldsA[64 * 64];
  __shared__ unsigned short ldsB[64 * 64];
  const int tid = threadIdx.x, w = tid >> 6, ln = tid & 63;
  const int bm = blockIdx.x, bn = blockIdx.y;
  const int wm = (w >> 1) * 32, wn = (w & 1) * 32;
  const f32x4 zf = {0.f, 0.f, 0.f, 0.f};
  f32x4 acc[2][2];
  #pragma unroll
  for (int i = 0; i < 2; i++)
    #pragma unroll
    for (int j = 0; j < 2; j++) acc[i][j] = zf;
  const int r8 = ln >> 3, s8 = ln & 7;
  for (int kt = 0; kt < K; kt += 64) {
    #pragma unroll
    for (int u = 0; u < 4; u++) {
      int jj = w * 4 + u;
      if (jj < 8) {
        gload16(A + (long)(bm * 64 + jj * 8 + r8) * K + kt + s8 * 8, &ldsA[jj * 512]);
      } else {
        int jb = jj - 8;
        gload16(Bt + (long)(bn * 64 + jb * 8 + r8) * K + kt + s8 * 8, &ldsB[jb * 512]);
      }
    }
    __syncthreads();
    #pragma unroll
    for (int kk = 0; kk < 2; kk++) {
      bf16x8 af[2], bfr[2];
      #pragma unroll
      for (int mf = 0; mf < 2; mf++)
        af[mf] = *(const bf16x8*)&ldsA[(wm + mf * 16 + (ln & 15)) * 64 + kk * 32 + (ln >> 4) * 8];
      #pragma unroll
      for (int nf = 0; nf < 2; nf++)
        bfr[nf] = *(const bf16x8*)&ldsB[(wn + nf * 16 + (ln & 15)) * 64 + kk * 32 + (ln >> 4) * 8];
      #pragma unroll
      for (int mf = 0; mf < 2; mf++)
        #pragma unroll
        for (int nf = 0; nf < 2; nf++)
          acc[mf][nf] = __builtin_amdgcn_mfma_f32_16x16x32_bf16(af[mf], bfr[nf], acc[mf][nf], 0, 0, 0);
    }
    __syncthreads();
  }
  const int g = ln >> 4, c = ln & 15;
  #pragma unroll
  for (int mf = 0; mf < 2; mf++) {
    #pragma unroll
    for (int nf = 0; nf < 2; nf++) {
      int col = bn * 64 + wn + nf * 16 + c;
      float bv = bias[col];
      if (EPI == 3 && col >= 1024) {
        // V column: write transposed into vt[((b*8+h)*64+hd)][s..s+3]
        long row0 = bm * 64 + wm + mf * 16 + g * 4;
        int b = (int)(row0 >> 11), s = (int)(row0 & 2047);
        int vc = col - 1024, h = vc >> 6, hd = vc & 63;
        ushort4 o;
        o.x = bf16r(acc[mf][nf][0] + bv);
        o.y = bf16r(acc[mf][nf][1] + bv);
        o.z = bf16r(acc[mf][nf][2] + bv);
        o.w = bf16r(acc[mf][nf][3] + bv);
        *(ushort4*)(vtout + ((long)((b * 8 + h) * 64 + hd)) * 2048 + s) = o;
      } else {
        #pragma unroll
        for (int j = 0; j < 4; j++) {
          long row = bm * 64 + wm + mf * 16 + g * 4 + j;
          float v = acc[mf][nf][j] + bv;
          if (EPI == 2) v = v > 0.f ? v : 0.f;
          ((unsigned short*)Cv)[row * N + col] = bf16r(v);
        }
      }
    }
  }
}

// ---------------- fused attention, FULL-K, 32x32 MFMA, in-register P ---------
// Round-13 structure (measured optimum): 2 buffers, 2 barriers/iter, no setprio.
__global__ __launch_bounds__(256, 4) void attn_kernel(
    const unsigned short* __restrict__ qkv,
    const unsigned short* __restrict__ vt,
    const float* __restrict__ mask,
    unsigned short* __restrict__ ao) {
  const int tid = threadIdx.x, w = tid >> 6, ln = tid & 63;
  const int lo = ln & 31, hi = ln >> 5;
  // XCD-aware bijective swizzle (512 = 8 x 64)
  const int bid = blockIdx.x + 16 * blockIdx.y;
  const int swz = (bid & 7) * 64 + (bid >> 3);
  const int qb = swz & 15, bh = swz >> 4;
  const int b = bh >> 3, h = bh & 7;
  const int q0 = qb * 128 + w * 32;
  const unsigned short* qp = qkv + (long)(b * 2048) * 1536 + h * 64;
  const unsigned short* kp = qp + 512;
  const unsigned short* vtp = vt + (long)bh * 64 * 2048;
  const float* mp = mask + b * 2048;

  __shared__ unsigned short sbuf[2][4096];   // 8KB per buffer
  __shared__ float mbuf[2048];
  __shared__ int mflag;

  {
    float acc = 0.f;
    #pragma unroll
    for (int i = 0; i < 8; i++) {
      float mv = mp[i * 256 + tid];
      mbuf[i * 256 + tid] = mv;
      acc += fabsf(mv);
    }
    if (tid == 0) mflag = 0;
    __syncthreads();
    if (acc != 0.f) mflag = 1;
    __syncthreads();
  }
  const bool anymask = (mflag != 0);

  const int jj0 = w * 2;
  const char *src0, *src1;
  long step;
  if (w < 2) {
    int r0 = jj0 * 8 + (ln >> 3), r1 = r0 + 8, s = ln & 7;
    src0 = (const char*)kp + 2L * ((long)r0 * 1536 + ((s ^ (r0 & 7)) * 8));
    src1 = (const char*)kp + 2L * ((long)r1 * 1536 + ((s ^ (r1 & 7)) * 8));
    step = 32L * 1536 * 2;
  } else {
    int j0 = (w - 2) * 2;
    int r0 = j0 * 16 + (ln >> 2), r1 = r0 + 16, s = ln & 3;
    src0 = (const char*)vtp + 2L * ((long)r0 * 2048 + ((s ^ ((r0 >> 1) & 3)) * 8));
    src1 = (const char*)vtp + 2L * ((long)r1 * 2048 + ((s ^ ((r1 >> 1) & 3)) * 8));
    step = 64;
  }
  unsigned short* const d0a = &sbuf[0][jj0 * 512];
  unsigned short* const d0b = d0a + 512;
  unsigned short* const d1a = &sbuf[1][jj0 * 512];
  unsigned short* const d1b = d1a + 512;

  int koffe[4];
  #pragma unroll
  for (int t = 0; t < 4; t++)
    koffe[t] = lo * 64 + (((t * 2 + hi) ^ (lo & 7)) * 8);
  int voffe[4];
  #pragma unroll
  for (int stt = 0; stt < 2; stt++)
    #pragma unroll
    for (int tau = 0; tau < 2; tau++) {
      int vr = tau * 32 + lo;
      voffe[stt * 2 + tau] = 2048 + vr * 32 + ((((stt * 2 + hi) ^ ((vr >> 1) & 3))) * 8);
    }

  bf16x8 qf[4];
  #pragma unroll
  for (int t = 0; t < 4; t++)
    qf[t] = *(const bf16x8*)(qp + (long)(q0 + lo) * 1536 + t * 16 + hi * 8);

  f32x16 oacc[2];
  #pragma unroll
  for (int t = 0; t < 2; t++)
    #pragma unroll
    for (int r = 0; r < 16; r++) oacc[t][r] = 0.f;
  float lsum = 0.f;
  const f32x16 zf16 = oacc[0];
  const float SC = 0.18033688011112042f;  // 0.125 * log2(e)

  gload16(src0, d0a);
  gload16(src1, d0b);
  src0 += step; src1 += step;

#define ATTN_BODY(CURB, DA, DB, ITOFF, STAGE_NEXT)                              \
  {                                                                             \
    if (STAGE_NEXT) {                                                           \
      gload16(src0, DA);                                                        \
      gload16(src1, DB);                                                        \
      src0 += step; src1 += step;                                               \
      asm volatile("s_waitcnt vmcnt(2)" ::: "memory");                          \
    } else {                                                                    \
      asm volatile("s_waitcnt vmcnt(0)" ::: "memory");                          \
    }                                                                           \
    __builtin_amdgcn_s_barrier();                                               \
    __builtin_amdgcn_sched_barrier(0);                                          \
    f32x16 sacc = zf16;                                                         \
    _Pragma("unroll")                                                           \
    for (int t = 0; t < 4; t++) {                                               \
      bf16x8 kf = *(const bf16x8*)&sbuf[CURB][koffe[t]];                        \
      sacc = __builtin_amdgcn_mfma_f32_32x32x16_bf16(kf, qf[t], sacc, 0, 0, 0); \
    }                                                                           \
    float e[16];                                                                \
    _Pragma("unroll")                                                           \
    for (int r = 0; r < 16; r++) e[r] = sacc[r] * SC;                           \
    if (anymask) {                                                              \
      float mval = mbuf[(ITOFF) + lo];                                          \
      _Pragma("unroll")                                                         \
      for (int r = 0; r < 16; r++)                                              \
        e[r] -= 1.4426950408889634e30f *                                        \
                __shfl(mval, (r & 3) + 8 * (r >> 2) + 4 * hi, 64);              \
    }                                                                           \
    _Pragma("unroll")                                                           \
    for (int r = 0; r < 16; r++) e[r] = __builtin_amdgcn_exp2f(e[r]);           \
    _Pragma("unroll")                                                           \
    for (int r = 0; r < 16; r++) lsum += e[r];                                  \
    unsigned int cv[8];                                                         \
    _Pragma("unroll")                                                           \
    for (int i = 0; i < 8; i++) cv[i] = pkbf16(e[2 * i], e[2 * i + 1]);         \
    _Pragma("unroll")                                                           \
    for (int stt = 0; stt < 2; stt++) {                                         \
      unsigned int pf[4];                                                       \
      {                                                                         \
        auto r0_ = __builtin_amdgcn_permlane32_swap(cv[stt * 4 + 0],            \
                                                    cv[stt * 4 + 2], false, false); \
        auto r1_ = __builtin_amdgcn_permlane32_swap(cv[stt * 4 + 1],            \
                                                    cv[stt * 4 + 3], false, false); \
        pf[0] = r0_[0]; pf[1] = r1_[0]; pf[2] = r0_[1]; pf[3] = r1_[1];         \
      }                                                                         \
      bf16x8 pfr = *(const bf16x8*)pf;                                          \
      _Pragma("unroll")                                                         \
      for (int tau = 0; tau < 2; tau++) {                                       \
        bf16x8 vf = *(const bf16x8*)&sbuf[CURB][voffe[stt * 2 + tau]];          \
        oacc[tau] = __builtin_amdgcn_mfma_f32_32x32x16_bf16(vf, pfr, oacc[tau], 0, 0, 0); \
      }                                                                         \
    }                                                                           \
    __builtin_amdgcn_sched_barrier(0);                                          \
    __builtin_amdgcn_s_barrier();                                               \
  }

  for (int it2 = 0; it2 < 32; it2++) {
    ATTN_BODY(0, d1a, d1b, it2 * 64, 1)
    ATTN_BODY(1, d0a, d0b, it2 * 64 + 32, (it2 < 31))
  }
#undef ATTN_BODY

  lsum += __shfl_xor(lsum, 32, 64);
  const float inv = 1.f / lsum;
  unsigned short* ob = ao + ((long)(b * 2048) + q0 + lo) * 512 + h * 64;
  #pragma unroll
  for (int tau = 0; tau < 2; tau++) {
    #pragma unroll
    for (int j = 0; j < 4; j++) {
      ushort4 o;
      o.x = bf16r(oacc[tau][4 * j + 0] * inv);
      o.y = bf16r(oacc[tau][4 * j + 1] * inv);
      o.z = bf16r(oacc[tau][4 * j + 2] * inv);
      o.w = bf16r(oacc[tau][4 * j + 3] * inv);
      *(ushort4*)(ob + tau * 32 + j * 8 + hi * 4) = o;
    }
  }
}

// ---------------- layernorm rows, bf16 in -> bf16 out ------------------------
__global__ __launch_bounds__(256) void ln_kernel(const unsigned short* __restrict__ in,
                                                 const float* __restrict__ gam,
                                                 const float* __restrict__ bet,
                                                 unsigned short* __restrict__ out) {
  const long row = blockIdx.x;
  const unsigned short* x = in + row * 512;
  float v0 = bf2f(x[threadIdx.x]), v1 = bf2f(x[threadIdx.x + 256]);
  float s = v0 + v1, ss = v0 * v0 + v1 * v1;
  #pragma unroll
  for (int off = 32; off > 0; off >>= 1) {
    s += __shfl_down(s, off, 64);
    ss += __shfl_down(ss, off, 64);
  }
  __shared__ float red[8];
  __shared__ float mv[2];
  int w = threadIdx.x >> 6, ln = threadIdx.x & 63;
  if (ln == 0) { red[w] = s; red[w + 4] = ss; }
  __syncthreads();
  if (threadIdx.x == 0) {
    float S = red[0] + red[1] + red[2] + red[3];
    float SS = red[4] + red[5] + red[6] + red[7];
    float mu = S * (1.f / 512.f);
    float var = SS * (1.f / 512.f) - mu * mu;
    mv[0] = mu;
    mv[1] = rsqrtf(var + 1e-5f);
  }
  __syncthreads();
  float mu = mv[0], rs = mv[1];
  float o0 = (v0 - mu) * rs * gam[threadIdx.x] + bet[threadIdx.x];
  float o1 = (v1 - mu) * rs * gam[threadIdx.x + 256] + bet[threadIdx.x + 256];
  out[row * 512 + threadIdx.x] = bf16r(o0);
  out[row * 512 + threadIdx.x + 256] = bf16r(o1);
}

// ---------------- LN2 (bf16 in/out) + fused alpha ----------------------------
__global__ __launch_bounds__(256) void ln2_alpha_kernel(const unsigned short* __restrict__ in,
                                                        const float* __restrict__ gam,
                                                        const float* __restrict__ bet,
                                                        const float* __restrict__ pw,
                                                        const float* __restrict__ pbias,
                                                        const float* __restrict__ mask,
                                                        unsigned short* __restrict__ out,
                                                        float* __restrict__ alpha) {
  const long row = blockIdx.x;
  const unsigned short* x = in + row * 512;
  float v0 = bf2f(x[threadIdx.x]), v1 = bf2f(x[threadIdx.x + 256]);
  float s = v0 + v1, ss = v0 * v0 + v1 * v1;
  #pragma unroll
  for (int off = 32; off > 0; off >>= 1) {
    s += __shfl_down(s, off, 64);
    ss += __shfl_down(ss, off, 64);
  }
  __shared__ float red[8];
  __shared__ float mv[2];
  __shared__ float pr[4][8];
  int w = threadIdx.x >> 6, ln = threadIdx.x & 63;
  if (ln == 0) { red[w] = s; red[w + 4] = ss; }
  __syncthreads();
  if (threadIdx.x == 0) {
    float S = red[0] + red[1] + red[2] + red[3];
    float SS = red[4] + red[5] + red[6] + red[7];
    float mu = S * (1.f / 512.f);
    float var = SS * (1.f / 512.f) - mu * mu;
    mv[0] = mu;
    mv[1] = rsqrtf(var + 1e-5f);
  }
  __syncthreads();
  float mu = mv[0], rs = mv[1];
  float o0 = (v0 - mu) * rs * gam[threadIdx.x] + bet[threadIdx.x];
  float o1 = (v1 - mu) * rs * gam[threadIdx.x + 256] + bet[threadIdx.x + 256];
  out[row * 512 + threadIdx.x] = bf16r(o0);
  out[row * 512 + threadIdx.x + 256] = bf16r(o1);
  // fused alpha: p[k] = sum_d t[row][d] * pw[d][k]
  float p[8];
  const float* w0 = pw + threadIdx.x * 8;
  const float* w1 = pw + (threadIdx.x + 256) * 8;
  #pragma unroll
  for (int k = 0; k < 8; k++) p[k] = o0 * w0[k] + o1 * w1[k];
  #pragma unroll
  for (int off = 32; off > 0; off >>= 1)
    #pragma unroll
    for (int k = 0; k < 8; k++) p[k] += __shfl_down(p[k], off, 64);
  if (ln == 0)
    #pragma unroll
    for (int k = 0; k < 8; k++) pr[w][k] = p[k];
  __syncthreads();
  if (threadIdx.x < 8) {
    float a = pr[0][threadIdx.x] + pr[1][threadIdx.x] + pr[2][threadIdx.x] + pr[3][threadIdx.x]
              + pbias[threadIdx.x];
    a = a < 0.f ? 0.01f * a : a;
    alpha[row * 8 + threadIdx.x] = a + mask[row] * (-1e16f);
  }
}

// ------- pool with fused per-batch softmax stats (redundant per block) -------
__global__ __launch_bounds__(256) void pool_kernel(const unsigned short* __restrict__ h,
                                                   const float* __restrict__ alpha,
                                                   float* __restrict__ partial) {
  int b = blockIdx.x >> 3, sc = blockIdx.x & 7;
  int w = threadIdx.x >> 6, ln = threadIdx.x & 63;
  __shared__ float red[4][8];
  __shared__ float Ms[8], Ss[8];
  __shared__ float wb[256];
  const float* ab = alpha + (long)b * 2048 * 8;
  float m[8];
  #pragma unroll
  for (int k = 0; k < 8; k++) m[k] = -1e38f;
  for (int s = threadIdx.x; s < 2048; s += 256) {
    const float* a = ab + (long)s * 8;
    #pragma unroll
    for (int k = 0; k < 8; k++) m[k] = fmaxf(m[k], a[k]);
  }
  #pragma unroll
  for (int off = 32; off > 0; off >>= 1)
    #pragma unroll
    for (int k = 0; k < 8; k++) m[k] = fmaxf(m[k], __shfl_down(m[k], off, 64));
  if (ln == 0)
    #pragma unroll
    for (int k = 0; k < 8; k++) red[w][k] = m[k];
  __syncthreads();
  if (threadIdx.x < 8)
    Ms[threadIdx.x] = fmaxf(fmaxf(red[0][threadIdx.x], red[1][threadIdx.x]),
                            fmaxf(red[2][threadIdx.x], red[3][threadIdx.x]));
  __syncthreads();
  float sm[8];
  #pragma unroll
  for (int k = 0; k < 8; k++) sm[k] = 0.f;
  for (int s = threadIdx.x; s < 2048; s += 256) {
    const float* a = ab + (long)s * 8;
    #pragma unroll
    for (int k = 0; k < 8; k++) sm[k] += __expf(a[k] - Ms[k]);
  }
  #pragma unroll
  for (int off = 32; off > 0; off >>= 1)
    #pragma unroll
    for (int k = 0; k < 8; k++) sm[k] += __shfl_down(sm[k], off, 64);
  __syncthreads();
  if (ln == 0)
    #pragma unroll
    for (int k = 0; k < 8; k++) red[w][k] = sm[k];
  __syncthreads();
  if (threadIdx.x < 8)
    Ss[threadIdx.x] = red[0][threadIdx.x] + red[1][threadIdx.x] +
                      red[2][threadIdx.x] + red[3][threadIdx.x];
  __syncthreads();
  int s0 = sc * 256;
  {
    const float* a = ab + (long)(s0 + threadIdx.x) * 8;
    float wsum = 0.f;
    #pragma unroll
    for (int ph = 0; ph < 8; ph++) wsum += __expf(a[ph] - Ms[ph]) / Ss[ph];
    wb[threadIdx.x] = wsum;
  }
  __syncthreads();
  float a0 = 0.f, a1 = 0.f;
  const unsigned short* hb = h + ((long)b * 2048 + s0) * 512;
  for (int i = 0; i < 256; i++) {
    float wv = wb[i];
    a0 += wv * bf2f(hb[(long)i * 512 + threadIdx.x]);
    a1 += wv * bf2f(hb[(long)i * 512 + threadIdx.x + 256]);
  }
  partial[(long)blockIdx.x * 512 + threadIdx.x] = a0;
  partial[(long)blockIdx.x * 512 + threadIdx.x + 256] = a1;
}

__global__ __launch_bounds__(256) void pool_final(const float* __restrict__ partial,
                                                  float* __restrict__ out) {
  int b = blockIdx.x;
  float a0 = 0.f, a1 = 0.f;
  #pragma unroll
  for (int sc = 0; sc < 8; sc++) {
    a0 += partial[(long)(b * 8 + sc) * 512 + threadIdx.x];
    a1 += partial[(long)(b * 8 + sc) * 512 + threadIdx.x + 256];
  }
  out[b * 512 + threadIdx.x] = a0;
  out[b * 512 + threadIdx.x + 256] = a1;
}

// -----------------------------------------------------------------------------
extern "C" void kernel_launch(void* const* d_in, const int* in_sizes, int n_in,
                              void* d_out, int out_size, void* d_ws, size_t ws_size,
                              hipStream_t stream) {
  (void)in_sizes; (void)n_in; (void)out_size;
  if (ws_size < 92274688UL) return;  // need ~88MB scratch

  const float* x    = (const float*)d_in[0];
  const float* mask = (const float*)d_in[1];
  const float* q1w = (const float*)d_in[2];  const float* q1b = (const float*)d_in[3];
  const float* k1w = (const float*)d_in[4];  const float* k1b = (const float*)d_in[5];
  const float* v1w = (const float*)d_in[6];  const float* v1b = (const float*)d_in[7];
  const float* o1w = (const float*)d_in[8];  const float* o1b = (const float*)d_in[9];
  const float* q2w = (const float*)d_in[10]; const float* q2b = (const float*)d_in[11];
  const float* k2w = (const float*)d_in[12]; const float* k2b = (const float*)d_in[13];
  const float* v2w = (const float*)d_in[14]; const float* v2b = (const float*)d_in[15];
  const float* o2w = (const float*)d_in[16]; const float* o2b = (const float*)d_in[17];
  const float* ln1g = (const float*)d_in[18]; const float* ln1b = (const float*)d_in[19];
  const float* fw1 = (const float*)d_in[20]; const float* fb1 = (const float*)d_in[21];
  const float* fw2 = (const float*)d_in[22]; const float* fb2 = (const float*)d_in[23];
  const float* ln2g = (const float*)d_in[24]; const float* ln2b = (const float*)d_in[25];
  const float* poolw = (const float*)d_in[26]; const float* poolb = (const float*)d_in[27];

  char* ws = (char*)d_ws;
  unsigned short* Wt  = (unsigned short*)(ws + 0);          // 10 x 512x512 bf16 (5MB)
  float* qb1          = (float*)(ws + 5242880);
  float* qb2          = (float*)(ws + 5249024);
  float* alpha        = (float*)(ws + 5255424);             // 256KB
  float* partial      = (float*)(ws + 5517568);             // 64KB
  unsigned short* qkv = (unsigned short*)(ws + 8388608);    // [8192][1536] bf16 (24MB)
  unsigned short* vt  = (unsigned short*)(ws + 33554432);   // [32][64][2048] bf16 (8MB)
  unsigned short* ao  = (unsigned short*)(ws + 41943040);   // [8192][512] bf16 (8MB)
  unsigned short* tb  = (unsigned short*)(ws + 50331648);   // [8192][512] bf16 (8MB)
  unsigned short* xn  = (unsigned short*)(ws + 67108864);   // [8192][512] bf16 (8MB)
  unsigned short* h1  = (unsigned short*)(ws + 75497472);   // (8MB)
  unsigned short* f   = (unsigned short*)(ws + 83886080);   // (8MB)
  unsigned short* h2  = xn;                                 // xn dead by then

  PrepArgs pa;
  pa.w[0] = q1w; pa.w[1] = k1w; pa.w[2] = v1w; pa.w[3] = o1w; pa.w[4] = fw1;
  pa.w[5] = fw2; pa.w[6] = q2w; pa.w[7] = k2w; pa.w[8] = v2w; pa.w[9] = o2w;
  pa.b1[0] = q1b; pa.b1[1] = k1b; pa.b1[2] = v1b;
  pa.b2[0] = q2b; pa.b2[1] = k2b; pa.b2[2] = v2b;

  prep_l2norm_kernel<<<8832, 256, 0, stream>>>(pa, Wt, qb1, qb2, x, xn);

  // layer 1 (QKV GEMM writes V directly transposed into vt), 64x64 tiles
  gemm64<3><<<dim3(128, 24), 256, 0, stream>>>(xn, Wt, qb1, qkv, 512, 1536, vt);
  attn_kernel<<<dim3(16, 32), 256, 0, stream>>>(qkv, vt, mask, ao);
  gemm64<1><<<dim3(128, 8), 256, 0, stream>>>(ao, Wt + 3L * 512 * 512, o1b, tb, 512, 512, nullptr);
  ln_kernel<<<8192, 256, 0, stream>>>(tb, ln1g, ln1b, h1);
  gemm64<2><<<dim3(128, 8), 256, 0, stream>>>(h1, Wt + 4L * 512 * 512, fb1, f, 512, 512, nullptr);
  gemm64<1><<<dim3(128, 8), 256, 0, stream>>>(f, Wt + 5L * 512 * 512, fb2, h2, 512, 512, nullptr);

  // layer 2
  gemm64<3><<<dim3(128, 24), 256, 0, stream>>>(h2, Wt + 6L * 512 * 512, qb2, qkv, 512, 1536, vt);
  attn_kernel<<<dim3(16, 32), 256, 0, stream>>>(qkv, vt, mask, ao);
  gemm64<1><<<dim3(128, 8), 256, 0, stream>>>(ao, Wt + 9L * 512 * 512, o2b, tb, 512, 512, nullptr);
  ln2_alpha_kernel<<<8192, 256, 0, stream>>>(tb, ln2g, ln2b, poolw, poolb, mask, tb, alpha);

  // pooling (stats fused into pool_kernel)
  pool_kernel<<<32, 256, 0, stream>>>(tb, alpha, partial);
  pool_final<<<4, 256, 0, stream>>>(partial, (float*)d_out);
}